// Round 1
// baseline (123.642 us; speedup 1.0000x reference)
//
#include <hip/hip_runtime.h>

// Problem constants (match reference setup)
#define BB     4
#define NW     128
#define HG     512
#define WG     512
#define EDIM   64
#define HIDDEN 768

// ---------------------------------------------------------------------------
// Kernel 1: compact projected-embedding table.
// ctab[b][n][e] = dot(emb[id(b,n)], proj[e]),  id(b,0)=0, id(b,n)=ids[b][n-1]
// grid: (ceil(129/4), BB) x 256 threads; thread t: e = t&63, n = bx*4 + t>>6
// ---------------------------------------------------------------------------
__global__ __launch_bounds__(256) void ctab_kernel(
    const float* __restrict__ emb,
    const float* __restrict__ proj,
    const int*   __restrict__ ids,
    float*       __restrict__ ctab)
{
    const int t = threadIdx.x;
    const int e = t & 63;
    const int n = blockIdx.x * 4 + (t >> 6);   // 0..131
    const int b = blockIdx.y;
    if (n > NW) return;

    const int id = (n == 0) ? 0 : ids[b * NW + (n - 1)];

    const float4* er = (const float4*)(emb + (size_t)id * HIDDEN);
    const float4* pr = (const float4*)(proj + (size_t)e * HIDDEN);

    float acc0 = 0.f, acc1 = 0.f;
    #pragma unroll 8
    for (int k = 0; k < HIDDEN / 8; ++k) {
        float4 a0 = er[2*k],     p0 = pr[2*k];
        float4 a1 = er[2*k + 1], p1 = pr[2*k + 1];
        acc0 += a0.x*p0.x + a0.y*p0.y + a0.z*p0.z + a0.w*p0.w;
        acc1 += a1.x*p1.x + a1.y*p1.y + a1.z*p1.z + a1.w*p1.w;
    }
    ctab[((size_t)b * (NW + 1) + n) * EDIM + e] = acc0 + acc1;
}

// ---------------------------------------------------------------------------
// Kernel 2: fused rasterize + gather + transpose-write.
// One block per (h, b). 256 threads.
//   phase 0: stage ctab[b] (129x64) in LDS with +1 padding (bank-conflict-free)
//   phase 1: filter the <=128 boxes down to those covering row h (~2-3)
//   phase 2: per-pixel winner = max priority of covering boxes (512 pixels)
//   phase 3: write 64 e-planes x 512 w, float4-coalesced
// ---------------------------------------------------------------------------
__global__ __launch_bounds__(256) void paint_kernel(
    const float* __restrict__ bbox,
    const int*   __restrict__ stride_p,
    const float* __restrict__ ctab,
    float*       __restrict__ out)
{
    const int h = blockIdx.x;
    const int b = blockIdx.y;
    const int t = threadIdx.x;
    const float s = (float)stride_p[0];

    __shared__ float tabs[NW + 1][EDIM + 1];   // 129 x 65 f32 = 33.5 KB
    __shared__ int   fw0[NW], fw1[NW], fpr[NW];
    __shared__ int   wns[WG];
    __shared__ int   cnt;

    if (t == 0) cnt = 0;
    __syncthreads();

    // stage compact table for this batch
    const float* cb = ctab + (size_t)b * (NW + 1) * EDIM;
    for (int i = t; i < (NW + 1) * EDIM; i += 256) {
        tabs[i >> 6][i & 63] = cb[i];
    }

    // filter boxes covering this row (order-independent: we max over prio)
    if (t < NW) {
        float4 bx = ((const float4*)bbox)[b * NW + t];
        int w0 = (int)rintf(bx.x / s);
        int h0 = (int)rintf(bx.y / s);
        int w1 = (int)rintf(bx.z / s);
        int h1 = (int)rintf(bx.w / s);
        if (h >= h0 && h < h1) {
            int idx = atomicAdd(&cnt, 1);
            fw0[idx] = w0; fw1[idx] = w1; fpr[idx] = t + 1;
        }
    }
    __syncthreads();

    // per-pixel winner (2 pixels per thread)
    const int nc = cnt;
    for (int w = t; w < WG; w += 256) {
        int wn = 0;
        for (int i = 0; i < nc; ++i) {
            if (w >= fw0[i] && w < fw1[i]) wn = max(wn, fpr[i]);
        }
        wns[w] = wn;
    }
    __syncthreads();

    // write: out[b][e][h][w] = tabs[wns[w]][e]
    float* orow = out + ((size_t)b * EDIM * HG + h) * WG;   // + e*HG*WG + w
    const int wq  = t & 127;        // float4 column index along w
    const int w0i = wq * 4;
    const int n0 = wns[w0i], n1 = wns[w0i + 1], n2 = wns[w0i + 2], n3 = wns[w0i + 3];
    #pragma unroll
    for (int e = t >> 7; e < EDIM; e += 2) {
        float4 v;
        v.x = tabs[n0][e];
        v.y = tabs[n1][e];
        v.z = tabs[n2][e];
        v.w = tabs[n3][e];
        ((float4*)(orow + (size_t)e * HG * WG))[wq] = v;
    }
}

// ---------------------------------------------------------------------------
extern "C" void kernel_launch(void* const* d_in, const int* in_sizes, int n_in,
                              void* d_out, int out_size, void* d_ws, size_t ws_size,
                              hipStream_t stream)
{
    // inputs per setup_inputs() order:
    // 0: img (unused, shape known), 1: bbox, 2: emb_weight, 3: proj_weight,
    // 4: input_ids, 5: stride
    const float* bbox = (const float*)d_in[1];
    const float* emb  = (const float*)d_in[2];
    const float* proj = (const float*)d_in[3];
    const int*   ids  = (const int*)d_in[4];
    const int*   strd = (const int*)d_in[5];

    float* out  = (float*)d_out;
    float* ctab = (float*)d_ws;   // BB * 129 * 64 f32 = 132 KB

    dim3 g1((NW + 1 + 3) / 4, BB);
    ctab_kernel<<<g1, 256, 0, stream>>>(emb, proj, ids, ctab);

    dim3 g2(HG, BB);
    paint_kernel<<<g2, 256, 0, stream>>>(bbox, strd, ctab, out);
}

// Round 2
// 81.696 us; speedup vs baseline: 1.5134x; 1.5134x over previous
//
#include <hip/hip_runtime.h>

// Problem constants (match reference setup)
#define BB     4
#define NW     128
#define HG     512
#define WG     512
#define EDIM   64
#define HIDDEN 768
#define CT_STRIDE 132          // 129 rounded up (alignment + guard)

typedef float f4 __attribute__((ext_vector_type(4)));

// d_ws layout (bytes):
//   ctabT : [BB][EDIM][CT_STRIDE] f32   @ 0        (135,168 B)
//   projT4: [HIDDEN/4][EDIM] f4         @ 135,168  (196,608 B)
//   winner: [BB][HG][WG] u8             @ 331,776  (1,048,576 B)
#define WS_CTABT  0
#define WS_PROJT  135168
#define WS_WINNER 331776

// ---------------------------------------------------------------------------
// Kernel 1 (prep): blocks 0..47 transpose proj -> projT4 (coalesce ctab loads);
// blocks 48..303 rasterize the max-priority winner map (u8), one block per
// (b, 8-row tile). Winner computed ONCE per pixel (not per e-plane).
// ---------------------------------------------------------------------------
__global__ __launch_bounds__(256) void prep_kernel(
    const float* __restrict__ bbox,
    const float* __restrict__ proj,
    const int*   __restrict__ stride_p,
    f4*          __restrict__ projT4,
    unsigned char* __restrict__ winner)
{
    const int t  = threadIdx.x;
    const int bx = blockIdx.x;

    if (bx < 48) {                       // transpose part
        const int idx = bx * 256 + t;    // 0..12287
        const int e = idx & 63, kk = idx >> 6;
        const f4* pr = (const f4*)(proj + (size_t)e * HIDDEN);
        projT4[kk * EDIM + e] = pr[kk];
        return;
    }

    // winner part: one block per (b, h-tile of 8 rows)
    const int wb = bx - 48;              // 0..255
    const int b  = wb >> 6;
    const int hbase = (wb & 63) * 8;
    const float s = (float)stride_p[0];

    __shared__ int fw0[NW], fw1[NW], fh0[NW], fh1[NW], fpr[NW];
    __shared__ int cnt;
    if (t == 0) cnt = 0;
    __syncthreads();

    if (t < NW) {
        float4 bv = ((const float4*)bbox)[b * NW + t];
        int w0 = (int)rintf(bv.x / s);
        int h0 = (int)rintf(bv.y / s);
        int w1 = (int)rintf(bv.z / s);
        int h1 = (int)rintf(bv.w / s);
        if (h1 > hbase && h0 < hbase + 8) {       // overlaps this tile
            int i = atomicAdd(&cnt, 1);
            fw0[i] = w0; fw1[i] = w1; fh0[i] = h0; fh1[i] = h1; fpr[i] = t + 1;
        }
    }
    __syncthreads();

    const int nc  = cnt;
    const int q   = t & 127;       // quad index along w
    const int w0p = q * 4;
    for (int rr = 0; rr < 4; ++rr) {
        const int row = hbase + rr * 2 + (t >> 7);
        int wn0 = 0, wn1 = 0, wn2 = 0, wn3 = 0;
        for (int i = 0; i < nc; ++i) {
            if (row >= fh0[i] && row < fh1[i]) {
                int a = fw0[i], z = fw1[i], p = fpr[i];
                if (w0p     >= a && w0p     < z) wn0 = max(wn0, p);
                if (w0p + 1 >= a && w0p + 1 < z) wn1 = max(wn1, p);
                if (w0p + 2 >= a && w0p + 2 < z) wn2 = max(wn2, p);
                if (w0p + 3 >= a && w0p + 3 < z) wn3 = max(wn3, p);
            }
        }
        uchar4 u;
        u.x = (unsigned char)wn0; u.y = (unsigned char)wn1;
        u.z = (unsigned char)wn2; u.w = (unsigned char)wn3;
        *(uchar4*)(winner + ((size_t)(b * HG + row)) * WG + w0p) = u;
    }
}

// ---------------------------------------------------------------------------
// Kernel 2: compact projected table, transposed: ctabT[b][e][n].
// All loads coalesced: emb row is wave-uniform (broadcast), projT4 is
// 16 B/lane contiguous across lanes.
// ---------------------------------------------------------------------------
__global__ __launch_bounds__(256) void ctab_kernel(
    const float* __restrict__ emb,
    const f4*    __restrict__ projT4,
    const int*   __restrict__ ids,
    float*       __restrict__ ctabT)
{
    const int t = threadIdx.x;
    const int e = t & 63;
    const int n = blockIdx.x * 4 + (t >> 6);   // 0..131
    const int b = blockIdx.y;
    if (n > NW) return;

    const int id = (n == 0) ? 0 : ids[b * NW + (n - 1)];
    const f4* er = (const f4*)(emb + (size_t)id * HIDDEN);

    float acc = 0.f;
    #pragma unroll 8
    for (int kk = 0; kk < HIDDEN / 4; ++kk) {
        f4 a = er[kk];                    // wave-uniform -> broadcast
        f4 p = projT4[kk * EDIM + e];     // lanes contiguous -> coalesced
        acc += a.x * p.x + a.y * p.y + a.z * p.z + a.w * p.w;
    }
    ctabT[((size_t)b * EDIM + e) * CT_STRIDE + n] = acc;
}

// ---------------------------------------------------------------------------
// Kernel 3: paint. One block per (b, e, 64-row tile): single contiguous
// 128 KB output stream per block. 129-float table column in LDS.
// ---------------------------------------------------------------------------
__global__ __launch_bounds__(256) void paint_kernel(
    const float*         __restrict__ ctabT,
    const unsigned char* __restrict__ winner,
    float*               __restrict__ out)
{
    const int t  = threadIdx.x;
    const int ht = blockIdx.x;   // 0..7   (64-row tiles)
    const int e  = blockIdx.y;   // 0..63
    const int b  = blockIdx.z;   // 0..3

    __shared__ float col[CT_STRIDE];
    if (t < CT_STRIDE) col[t] = ctabT[((size_t)b * EDIM + e) * CT_STRIDE + t];
    __syncthreads();

    const int h0 = ht * 64;
    const uchar4* wrow = (const uchar4*)(winner + ((size_t)(b * HG + h0)) * WG);
    f4* obase = (f4*)(out + ((size_t)(b * EDIM + e) * HG + h0) * WG);

    #pragma unroll 4
    for (int i = 0; i < 32; ++i) {
        const int q = t + i * 256;            // 0..8191 quads (64 rows x 512)
        uchar4 wn = wrow[q];
        f4 v;
        v.x = col[wn.x];
        v.y = col[wn.y];
        v.z = col[wn.z];
        v.w = col[wn.w];
        __builtin_nontemporal_store(v, obase + q);
    }
}

// ---------------------------------------------------------------------------
extern "C" void kernel_launch(void* const* d_in, const int* in_sizes, int n_in,
                              void* d_out, int out_size, void* d_ws, size_t ws_size,
                              hipStream_t stream)
{
    // inputs: 0 img (unused), 1 bbox, 2 emb_weight, 3 proj_weight,
    //         4 input_ids, 5 stride
    const float* bbox = (const float*)d_in[1];
    const float* emb  = (const float*)d_in[2];
    const float* proj = (const float*)d_in[3];
    const int*   ids  = (const int*)d_in[4];
    const int*   strd = (const int*)d_in[5];

    float* out = (float*)d_out;
    char*  ws  = (char*)d_ws;
    float*         ctabT  = (float*)(ws + WS_CTABT);
    f4*            projT4 = (f4*)(ws + WS_PROJT);
    unsigned char* winner = (unsigned char*)(ws + WS_WINNER);

    prep_kernel<<<48 + BB * (HG / 8), 256, 0, stream>>>(bbox, proj, strd, projT4, winner);

    dim3 g2((NW + 1 + 3) / 4, BB);
    ctab_kernel<<<g2, 256, 0, stream>>>(emb, projT4, ids, ctabT);

    dim3 g3(HG / 64, EDIM, BB);
    paint_kernel<<<g3, 256, 0, stream>>>(ctabT, winner, out);
}